// Round 3
// baseline (351.218 us; speedup 1.0000x reference)
//
#include <hip/hip_runtime.h>
#include <hip/hip_bf16.h>
#include <math.h>

// MoE: B=2,S=1024,D=1024,E=8,H=3584, top-1 routing.
// router -> aux -> scatter -> gemm12 (x@W1^T, x@W2^T fused + SwiGLU -> h bf16)
//                          -> gemm3  (h@W3^T, split-K=2, atomicAdd f32 -> out)
// GEMMs: bf16 MFMA 16x16x32, f32 acc, double-buffered LDS, 2-set register pipeline.

#define NB 2
#define NS 1024
#define ND 1024
#define NE 8
#define NH 3584
#define NTOK 2048
#define LDK 72   // +8 bf16 pad -> 144B row stride

typedef float f32x4 __attribute__((ext_vector_type(4)));
typedef __bf16 bf16x8 __attribute__((ext_vector_type(8)));
typedef unsigned short u16x4 __attribute__((ext_vector_type(4)));
typedef unsigned int u32x4 __attribute__((ext_vector_type(4)));

__device__ __forceinline__ u16x4 cvt4(f32x4 v) {
  u16x4 r;
  r[0] = __builtin_bit_cast(unsigned short, (__bf16)v[0]);
  r[1] = __builtin_bit_cast(unsigned short, (__bf16)v[1]);
  r[2] = __builtin_bit_cast(unsigned short, (__bf16)v[2]);
  r[3] = __builtin_bit_cast(unsigned short, (__bf16)v[3]);
  return r;
}

struct R12 { f32x4 a[8]; f32x4 b1[4]; f32x4 b2[4]; };
struct R3  { u32x4 a[4]; f32x4 b[4]; };

// ---------------- router ----------------
__global__ __launch_bounds__(256) void router_kernel(
    const float* __restrict__ x, const float* __restrict__ Wr,
    float* __restrict__ probs, float* __restrict__ lse,
    int* __restrict__ counts, int* __restrict__ expert_of)
{
  int n = blockIdx.x;
  int t = threadIdx.x;
  const float* xr = x + (size_t)n * ND;
  float xv[4];
#pragma unroll
  for (int j = 0; j < 4; ++j) xv[j] = xr[t + j * 256];
  float p[NE];
#pragma unroll
  for (int e = 0; e < NE; ++e) p[e] = 0.f;
#pragma unroll
  for (int j = 0; j < 4; ++j) {
    int d = t + j * 256;
#pragma unroll
    for (int e = 0; e < NE; ++e) p[e] += xv[j] * Wr[e * ND + d];
  }
#pragma unroll
  for (int e = 0; e < NE; ++e) {
#pragma unroll
    for (int o = 32; o > 0; o >>= 1) p[e] += __shfl_down(p[e], o, 64);
  }
  __shared__ float red[4][NE];
  int wid = t >> 6, lane = t & 63;
  if (lane == 0) {
#pragma unroll
    for (int e = 0; e < NE; ++e) red[wid][e] = p[e];
  }
  __syncthreads();
  if (t == 0) {
    float lg[NE];
#pragma unroll
    for (int e = 0; e < NE; ++e) lg[e] = red[0][e] + red[1][e] + red[2][e] + red[3][e];
    float m = lg[0]; int arg = 0;
#pragma unroll
    for (int e = 1; e < NE; ++e) if (lg[e] > m) { m = lg[e]; arg = e; }
    float s = 0.f, ex[NE];
#pragma unroll
    for (int e = 0; e < NE; ++e) { ex[e] = expf(lg[e] - m); s += ex[e]; }
    float inv = 1.f / s;
#pragma unroll
    for (int e = 0; e < NE; ++e) probs[n * NE + e] = ex[e] * inv;
    lse[n] = m + logf(s);
    expert_of[n] = arg;
    atomicAdd(&counts[arg], 1);
  }
}

// ---------------- aux losses + offsets ----------------
__global__ __launch_bounds__(256) void aux_offsets_kernel(
    const float* __restrict__ probs, const float* __restrict__ lse,
    const int* __restrict__ counts, int* __restrict__ offsets,
    int* __restrict__ cursors, float* __restrict__ out_aux)
{
  int t = threadIdx.x;
  float lsum = 0.f;
  for (int n = t; n < NTOK; n += 256) lsum += lse[n];
  float esum = 0.f, esq = 0.f;
  for (int i = t; i < NS * NE; i += 256) {
    float v = probs[i] + probs[NS * NE + i];
    esum += v; esq += v * v;
  }
  __shared__ float rb[3][4];
  int wid = t >> 6, lane = t & 63;
#pragma unroll
  for (int o = 32; o > 0; o >>= 1) {
    lsum += __shfl_down(lsum, o, 64);
    esum += __shfl_down(esum, o, 64);
    esq  += __shfl_down(esq, o, 64);
  }
  if (lane == 0) { rb[0][wid] = lsum; rb[1][wid] = esum; rb[2][wid] = esq; }
  __syncthreads();
  if (t == 0) {
    lsum = rb[0][0] + rb[0][1] + rb[0][2] + rb[0][3];
    esum = rb[1][0] + rb[1][1] + rb[1][2] + rb[1][3];
    esq  = rb[2][0] + rb[2][1] + rb[2][2] + rb[2][3];
    float zmean = lsum / (float)NTOK;
    float z_loss = zmean * zmean;
    const float nn = (float)(NS * NE);
    float mean = esum / nn;
    float var = (esq - esum * esum / nn) / (nn - 1.0f);
    float load_loss = var / (mean * mean);
    out_aux[0] = 1e-3f * z_loss + 1e-3f * load_loss;
    int off = 0;
#pragma unroll
    for (int e = 0; e < NE; ++e) { offsets[e] = off; cursors[e] = off; off += counts[e]; }
    offsets[NE] = off;
  }
}

// ---------------- token lists ----------------
__global__ __launch_bounds__(256) void scatter_kernel(
    const int* __restrict__ expert_of, int* __restrict__ cursors,
    int* __restrict__ token_list)
{
  int n = blockIdx.x * 256 + threadIdx.x;
  int e = expert_of[n];
  int p = atomicAdd(&cursors[e], 1);
  token_list[p] = n;
}

// ---------------- fused GEMM12 + SwiGLU ----------------
// BM=128 x BN=64, BK=64, 4 waves 2x2; double-buffered LDS, 2-set reg pipeline.
__global__ __launch_bounds__(256, 2) void moe_gemm12(
    const float* __restrict__ x, const float* __restrict__ W1f,
    const float* __restrict__ W2f, const int* __restrict__ offsets,
    const int* __restrict__ token_list, unsigned short* __restrict__ h)
{
  int e = blockIdx.z;
  int base = offsets[e], cnt = offsets[e + 1] - base;
  int m0 = blockIdx.y * 128;
  if (m0 >= cnt) return;
  int n0 = blockIdx.x * 64;
  const float* B1 = W1f + (size_t)e * ((size_t)NH * ND) + (size_t)n0 * ND;
  const float* B2 = W2f + (size_t)e * ((size_t)NH * ND) + (size_t)n0 * ND;

  __shared__ __align__(16) unsigned short As[2][128][LDK];
  __shared__ __align__(16) unsigned short B1s[2][64][LDK];
  __shared__ __align__(16) unsigned short B2s[2][64][LDK];
  __shared__ int rowtok[128];

  int t = threadIdx.x;
  if (t < 128) {
    int mc = m0 + t; if (mc > cnt - 1) mc = cnt - 1;
    rowtok[t] = token_list[base + mc];
  }
  __syncthreads();

  int rsub = t >> 4;            // 0..15
  int c4 = (t & 15) * 4;        // f32 col within BK

  const float* asrc[8];
#pragma unroll
  for (int rr = 0; rr < 8; ++rr)
    asrc[rr] = x + (size_t)rowtok[rr * 16 + rsub] * ND + c4;
  const float* b1src = B1 + (size_t)rsub * ND + c4;
  const float* b2src = B2 + (size_t)rsub * ND + c4;

  auto load12 = [&](R12& r, int k0) {
#pragma unroll
    for (int rr = 0; rr < 8; ++rr) r.a[rr] = *(const f32x4*)(asrc[rr] + k0);
#pragma unroll
    for (int rr = 0; rr < 4; ++rr) {
      r.b1[rr] = *(const f32x4*)(b1src + (size_t)rr * 16 * ND + k0);
      r.b2[rr] = *(const f32x4*)(b2src + (size_t)rr * 16 * ND + k0);
    }
  };
  auto store12 = [&](int buf, const R12& r) {
#pragma unroll
    for (int rr = 0; rr < 8; ++rr)
      *(u16x4*)&As[buf][rr * 16 + rsub][c4] = cvt4(r.a[rr]);
#pragma unroll
    for (int rr = 0; rr < 4; ++rr) {
      *(u16x4*)&B1s[buf][rr * 16 + rsub][c4] = cvt4(r.b1[rr]);
      *(u16x4*)&B2s[buf][rr * 16 + rsub][c4] = cvt4(r.b2[rr]);
    }
  };

  int lane = t & 63, wid = t >> 6;
  int wm = (wid >> 1) * 64;   // 0 / 64
  int wn = (wid & 1) * 32;    // 0 / 32
  int rl = lane & 15;
  int ksel = (lane >> 4) * 8;

  f32x4 acc1[4][2] = {}, acc2[4][2] = {};

  auto mfma12 = [&](int buf) {
#pragma unroll
    for (int kk = 0; kk < 2; ++kk) {
      int klo = kk * 32 + ksel;
      bf16x8 af[4], b1[2], b2[2];
#pragma unroll
      for (int i = 0; i < 4; ++i) af[i] = *(const bf16x8*)&As[buf][wm + i * 16 + rl][klo];
#pragma unroll
      for (int j = 0; j < 2; ++j) {
        b1[j] = *(const bf16x8*)&B1s[buf][wn + j * 16 + rl][klo];
        b2[j] = *(const bf16x8*)&B2s[buf][wn + j * 16 + rl][klo];
      }
#pragma unroll
      for (int i = 0; i < 4; ++i)
#pragma unroll
        for (int j = 0; j < 2; ++j) {
          acc1[i][j] = __builtin_amdgcn_mfma_f32_16x16x32_bf16(af[i], b1[j], acc1[i][j], 0, 0, 0);
          acc2[i][j] = __builtin_amdgcn_mfma_f32_16x16x32_bf16(af[i], b2[j], acc2[i][j], 0, 0, 0);
        }
    }
  };

  R12 r0, r1;
  load12(r0, 0);
  load12(r1, 64);
  store12(0, r0);
  __syncthreads();

  const int NSTEP = ND / 64;   // 16, even
  for (int ks = 0; ks < NSTEP; ks += 2) {
    if (ks + 2 < NSTEP) load12(r0, (ks + 2) * 64);
    mfma12(0);
    store12(1, r1);            // step ks+1
    __syncthreads();
    if (ks + 3 < NSTEP) load12(r1, (ks + 3) * 64);
    mfma12(1);
    if (ks + 2 < NSTEP) store12(0, r0);
    __syncthreads();
  }

  // SwiGLU epilogue in f32, write h bf16 (list order)
  int rq = lane >> 4;
#pragma unroll
  for (int i = 0; i < 4; ++i)
#pragma unroll
    for (int r = 0; r < 4; ++r) {
      int mrow = wm + i * 16 + rq * 4 + r;
      int m = m0 + mrow;
      if (m < cnt) {
#pragma unroll
        for (int j = 0; j < 2; ++j) {
          int col = n0 + wn + j * 16 + rl;
          float g1 = acc1[i][j][r], g2 = acc2[i][j][r];
          float hv = g1 / (1.f + expf(-g1)) * g2;
          h[(size_t)(base + m) * NH + col] = __builtin_bit_cast(unsigned short, (__bf16)hv);
        }
      }
    }
}

// ---------------- GEMM3: out += h @ W3^T (split-K=2, atomicAdd) ----------------
__global__ __launch_bounds__(256, 2) void moe_gemm3(
    const unsigned short* __restrict__ h, const float* __restrict__ W3f,
    const int* __restrict__ offsets, const int* __restrict__ token_list,
    float* __restrict__ out)
{
  int e = blockIdx.z;
  int base = offsets[e], cnt = offsets[e + 1] - base;
  int m0 = blockIdx.y * 128;
  if (m0 >= cnt) return;
  int n0 = (blockIdx.x >> 1) * 64;
  int kc = blockIdx.x & 1;            // split-K half
  const int KOFF = kc * (NH / 2);     // bf16-element K offset (1792)
  const float* B = W3f + (size_t)e * ((size_t)ND * NH) + (size_t)n0 * NH + KOFF;

  __shared__ __align__(16) unsigned short As[2][128][LDK];
  __shared__ __align__(16) unsigned short Bs[2][64][LDK];
  __shared__ int rowtok[128];

  int t = threadIdx.x;
  if (t < 128) {
    int mc = m0 + t; if (mc > cnt - 1) mc = cnt - 1;
    rowtok[t] = token_list[base + mc];
  }
  __syncthreads();

  int rsub8 = t >> 3;           // 0..31
  int c8 = (t & 7) * 8;         // bf16 col
  const unsigned short* asrc[4];
#pragma unroll
  for (int rr = 0; rr < 4; ++rr) {
    int row = rr * 32 + rsub8;
    int mc = m0 + row; if (mc > cnt - 1) mc = cnt - 1;
    asrc[rr] = h + (size_t)(base + mc) * NH + KOFF + c8;
  }
  int rsub = t >> 4;
  int c4 = (t & 15) * 4;
  const float* bsrc = B + (size_t)rsub * NH + c4;

  auto load3 = [&](R3& r, int k0) {
#pragma unroll
    for (int rr = 0; rr < 4; ++rr) r.a[rr] = *(const u32x4*)(asrc[rr] + k0);
#pragma unroll
    for (int rr = 0; rr < 4; ++rr) r.b[rr] = *(const f32x4*)(bsrc + (size_t)rr * 16 * NH + k0);
  };
  auto store3 = [&](int buf, const R3& r) {
#pragma unroll
    for (int rr = 0; rr < 4; ++rr) *(u32x4*)&As[buf][rr * 32 + rsub8][c8] = r.a[rr];
#pragma unroll
    for (int rr = 0; rr < 4; ++rr)
      *(u16x4*)&Bs[buf][rr * 16 + rsub][c4] = cvt4(r.b[rr]);
  };

  int lane = t & 63, wid = t >> 6;
  int wm = (wid >> 1) * 64;
  int wn = (wid & 1) * 32;
  int rl = lane & 15;
  int ksel = (lane >> 4) * 8;

  f32x4 acc[4][2] = {};

  auto mfma3 = [&](int buf) {
#pragma unroll
    for (int kk = 0; kk < 2; ++kk) {
      int klo = kk * 32 + ksel;
      bf16x8 af[4], bv[2];
#pragma unroll
      for (int i = 0; i < 4; ++i) af[i] = *(const bf16x8*)&As[buf][wm + i * 16 + rl][klo];
#pragma unroll
      for (int j = 0; j < 2; ++j) bv[j] = *(const bf16x8*)&Bs[buf][wn + j * 16 + rl][klo];
#pragma unroll
      for (int i = 0; i < 4; ++i)
#pragma unroll
        for (int j = 0; j < 2; ++j)
          acc[i][j] = __builtin_amdgcn_mfma_f32_16x16x32_bf16(af[i], bv[j], acc[i][j], 0, 0, 0);
    }
  };

  R3 r0, r1;
  load3(r0, 0);
  load3(r1, 64);
  store3(0, r0);
  __syncthreads();

  const int NSTEP = (NH / 2) / 64;   // 28, even
  for (int ks = 0; ks < NSTEP; ks += 2) {
    if (ks + 2 < NSTEP) load3(r0, (ks + 2) * 64);
    mfma3(0);
    store3(1, r1);
    __syncthreads();
    if (ks + 3 < NSTEP) load3(r1, (ks + 3) * 64);
    mfma3(1);
    if (ks + 2 < NSTEP) store3(0, r0);
    __syncthreads();
  }

  int rq = lane >> 4;
#pragma unroll
  for (int i = 0; i < 4; ++i)
#pragma unroll
    for (int r = 0; r < 4; ++r) {
      int mrow = wm + i * 16 + rq * 4 + r;
      int m = m0 + mrow;
      if (m < cnt) {
        int tok = rowtok[mrow];
#pragma unroll
        for (int j = 0; j < 2; ++j) {
          int col = n0 + wn + j * 16 + rl;
          atomicAdd(&out[(size_t)tok * ND + col], acc[i][j][r]);
        }
      }
    }
}

extern "C" void kernel_launch(void* const* d_in, const int* in_sizes, int n_in,
                              void* d_out, int out_size, void* d_ws, size_t ws_size,
                              hipStream_t stream)
{
  (void)in_sizes; (void)n_in; (void)out_size; (void)ws_size;
  const float* x  = (const float*)d_in[0];
  const float* Wr = (const float*)d_in[1];
  const float* W1 = (const float*)d_in[2];
  const float* W2 = (const float*)d_in[3];
  const float* W3 = (const float*)d_in[4];
  float* out = (float*)d_out;

  char* w = (char*)d_ws;
  float* probs    = (float*)(w + 0);        // 65536 B
  float* lse      = (float*)(w + 65536);    // 8192 B
  int* counts     = (int*)(w + 73728);      // 32 B
  int* cursors    = (int*)(w + 73760);      // 32 B
  int* offsets    = (int*)(w + 73792);      // 64 B
  int* expert_of  = (int*)(w + 73856);      // 8192 B
  int* token_list = (int*)(w + 82048);      // 8192 B
  unsigned short* h = (unsigned short*)(w + 131072);   // NTOK*NH*2 = 14680064 B

  hipMemsetAsync(counts, 0, 32, stream);
  hipMemsetAsync(out, 0, (size_t)NTOK * ND * sizeof(float), stream);  // split-K accum target
  router_kernel<<<NTOK, 256, 0, stream>>>(x, Wr, probs, lse, counts, expert_of);
  aux_offsets_kernel<<<1, 256, 0, stream>>>(probs, lse, counts, offsets, cursors,
                                            out + (size_t)NTOK * ND);
  scatter_kernel<<<NTOK / 256, 256, 0, stream>>>(expert_of, cursors, token_list);
  moe_gemm12<<<dim3(NH / 64, NTOK / 128, NE), 256, 0, stream>>>(
      x, W1, W2, offsets, token_list, h);
  moe_gemm3<<<dim3((ND / 64) * 2, NTOK / 128, NE), 256, 0, stream>>>(
      h, W3, offsets, token_list, out);
}

// Round 4
// 210.298 us; speedup vs baseline: 1.6701x; 1.6701x over previous
//
#include <hip/hip_runtime.h>
#include <hip/hip_bf16.h>
#include <math.h>

// MoE: B=2,S=1024,D=1024,E=8,H=3584, top-1 routing.
// convert_x -> router -> aux -> scatter
//   -> gemm12 (x@W1^T, x@W2^T fused + SwiGLU -> h bf16): A via global_load_lds DMA
//      (swizzled source), B via 2-set reg-staged f32->bf16, dbuf LDS.
//   -> gemm3 (h@W3^T, split-K=2, atomicAdd f32 -> out): same structure.

#define NS 1024
#define ND 1024
#define NE 8
#define NH 3584
#define NTOK 2048
#define LDK 72   // +8 bf16 pad for B tiles

typedef float f32x4 __attribute__((ext_vector_type(4)));
typedef __bf16 bf16x8 __attribute__((ext_vector_type(8)));
typedef unsigned short u16x4 __attribute__((ext_vector_type(4)));
typedef unsigned int u32x4 __attribute__((ext_vector_type(4)));

__device__ __forceinline__ u16x4 cvt4(f32x4 v) {
  u16x4 r;
  r[0] = __builtin_bit_cast(unsigned short, (__bf16)v[0]);
  r[1] = __builtin_bit_cast(unsigned short, (__bf16)v[1]);
  r[2] = __builtin_bit_cast(unsigned short, (__bf16)v[2]);
  r[3] = __builtin_bit_cast(unsigned short, (__bf16)v[3]);
  return r;
}

__device__ __forceinline__ void gl_lds16(const void* g, void* l) {
  __builtin_amdgcn_global_load_lds(
      (const __attribute__((address_space(1))) unsigned int*)g,
      (__attribute__((address_space(3))) unsigned int*)l, 16, 0, 0);
}

// ---------------- x f32 -> bf16 ----------------
__global__ __launch_bounds__(256) void convert_x(
    const float* __restrict__ x, unsigned short* __restrict__ xb)
{
  size_t i = ((size_t)blockIdx.x * 256 + threadIdx.x) * 4;
  f32x4 v = *(const f32x4*)(x + i);
  *(u16x4*)(xb + i) = cvt4(v);
}

// ---------------- router ----------------
__global__ __launch_bounds__(256) void router_kernel(
    const float* __restrict__ x, const float* __restrict__ Wr,
    float* __restrict__ probs, float* __restrict__ lse,
    int* __restrict__ counts, int* __restrict__ expert_of)
{
  int n = blockIdx.x;
  int t = threadIdx.x;
  const float* xr = x + (size_t)n * ND;
  float xv[4];
#pragma unroll
  for (int j = 0; j < 4; ++j) xv[j] = xr[t + j * 256];
  float p[NE];
#pragma unroll
  for (int e = 0; e < NE; ++e) p[e] = 0.f;
#pragma unroll
  for (int j = 0; j < 4; ++j) {
    int d = t + j * 256;
#pragma unroll
    for (int e = 0; e < NE; ++e) p[e] += xv[j] * Wr[e * ND + d];
  }
#pragma unroll
  for (int e = 0; e < NE; ++e) {
#pragma unroll
    for (int o = 32; o > 0; o >>= 1) p[e] += __shfl_down(p[e], o, 64);
  }
  __shared__ float red[4][NE];
  int wid = t >> 6, lane = t & 63;
  if (lane == 0) {
#pragma unroll
    for (int e = 0; e < NE; ++e) red[wid][e] = p[e];
  }
  __syncthreads();
  if (t == 0) {
    float lg[NE];
#pragma unroll
    for (int e = 0; e < NE; ++e) lg[e] = red[0][e] + red[1][e] + red[2][e] + red[3][e];
    float m = lg[0]; int arg = 0;
#pragma unroll
    for (int e = 1; e < NE; ++e) if (lg[e] > m) { m = lg[e]; arg = e; }
    float s = 0.f, ex[NE];
#pragma unroll
    for (int e = 0; e < NE; ++e) { ex[e] = expf(lg[e] - m); s += ex[e]; }
    float inv = 1.f / s;
#pragma unroll
    for (int e = 0; e < NE; ++e) probs[n * NE + e] = ex[e] * inv;
    lse[n] = m + logf(s);
    expert_of[n] = arg;
    atomicAdd(&counts[arg], 1);
  }
}

// ---------------- aux losses + offsets ----------------
__global__ __launch_bounds__(256) void aux_offsets_kernel(
    const float* __restrict__ probs, const float* __restrict__ lse,
    const int* __restrict__ counts, int* __restrict__ offsets,
    int* __restrict__ cursors, float* __restrict__ out_aux)
{
  int t = threadIdx.x;
  float lsum = 0.f;
  for (int n = t; n < NTOK; n += 256) lsum += lse[n];
  float esum = 0.f, esq = 0.f;
  for (int i = t; i < NS * NE; i += 256) {
    float v = probs[i] + probs[NS * NE + i];
    esum += v; esq += v * v;
  }
  __shared__ float rb[3][4];
  int wid = t >> 6, lane = t & 63;
#pragma unroll
  for (int o = 32; o > 0; o >>= 1) {
    lsum += __shfl_down(lsum, o, 64);
    esum += __shfl_down(esum, o, 64);
    esq  += __shfl_down(esq, o, 64);
  }
  if (lane == 0) { rb[0][wid] = lsum; rb[1][wid] = esum; rb[2][wid] = esq; }
  __syncthreads();
  if (t == 0) {
    lsum = rb[0][0] + rb[0][1] + rb[0][2] + rb[0][3];
    esum = rb[1][0] + rb[1][1] + rb[1][2] + rb[1][3];
    esq  = rb[2][0] + rb[2][1] + rb[2][2] + rb[2][3];
    float zmean = lsum / (float)NTOK;
    float z_loss = zmean * zmean;
    const float nn = (float)(NS * NE);
    float mean = esum / nn;
    float var = (esq - esum * esum / nn) / (nn - 1.0f);
    float load_loss = var / (mean * mean);
    out_aux[0] = 1e-3f * z_loss + 1e-3f * load_loss;
    int off = 0;
#pragma unroll
    for (int e = 0; e < NE; ++e) { offsets[e] = off; cursors[e] = off; off += counts[e]; }
    offsets[NE] = off;
  }
}

// ---------------- token lists ----------------
__global__ __launch_bounds__(256) void scatter_kernel(
    const int* __restrict__ expert_of, int* __restrict__ cursors,
    int* __restrict__ token_list)
{
  int n = blockIdx.x * 256 + threadIdx.x;
  int e = expert_of[n];
  int p = atomicAdd(&cursors[e], 1);
  token_list[p] = n;
}

// ---------------- fused GEMM12 + SwiGLU ----------------
// BM=128 x BN=64, BK=64, 4 waves 2x2. A (bf16) via global_load_lds DMA with
// XOR-swizzled source; B1/B2 reg-staged f32->bf16, 2 sets (~1.5-step prefetch).
__global__ __launch_bounds__(256) void moe_gemm12(
    const unsigned short* __restrict__ xb, const float* __restrict__ W1f,
    const float* __restrict__ W2f, const int* __restrict__ offsets,
    const int* __restrict__ token_list, unsigned short* __restrict__ h)
{
  int e = blockIdx.z;
  int base = offsets[e], cnt = offsets[e + 1] - base;
  int m0 = blockIdx.y * 128;
  if (m0 >= cnt) return;
  int n0 = blockIdx.x * 64;
  const float* B1 = W1f + (size_t)e * ((size_t)NH * ND) + (size_t)n0 * ND;
  const float* B2 = W2f + (size_t)e * ((size_t)NH * ND) + (size_t)n0 * ND;

  __shared__ __align__(16) unsigned short As[2][128][64];   // linear, XOR-swizzled content
  __shared__ __align__(16) unsigned short B1s[2][64][LDK];
  __shared__ __align__(16) unsigned short B2s[2][64][LDK];
  __shared__ int rowtok[128];

  int t = threadIdx.x;
  if (t < 128) {
    int mc = m0 + t; if (mc > cnt - 1) mc = cnt - 1;
    rowtok[t] = token_list[base + mc];
  }
  __syncthreads();

  int lane = t & 63, wid = t >> 6;

  // --- A DMA setup: wave w stages rows w*32..w*32+31 (4 issues x 1KB) ---
  // lane l: row (l>>3) within 8-row chunk, 16B-block (l&7); source block
  // pre-swizzled by ^(row&7) so reads can XOR the same way.
  const char* aSrc[4];
  {
    int l8 = lane >> 3, blk = lane & 7;
    int sblk = blk ^ l8;          // (l&7) ^ (R&7), R&7 == l>>3
#pragma unroll
    for (int i = 0; i < 4; ++i) {
      int R = wid * 32 + i * 8 + l8;
      aSrc[i] = (const char*)(xb + (size_t)rowtok[R] * ND + sblk * 8);
    }
  }
  unsigned aldsOff = wid * 4096;

  auto stageA = [&](int buf, int ks) {
    char* dst = (char*)&As[buf][0][0] + aldsOff;
#pragma unroll
    for (int i = 0; i < 4; ++i)
      gl_lds16(aSrc[i] + ks * 128, dst + i * 1024);
  };

  // --- B staging: 2 register sets ---
  int rsub = t >> 4;            // 0..15
  int c4 = (t & 15) * 4;        // f32 col
  const float* b1p = B1 + (size_t)rsub * ND + c4;
  const float* b2p = B2 + (size_t)rsub * ND + c4;

  f32x4 s0b1[4], s0b2[4], s1b1[4], s1b2[4];

  auto loadB_s0 = [&](int k0) {
#pragma unroll
    for (int rr = 0; rr < 4; ++rr) {
      s0b1[rr] = *(const f32x4*)(b1p + (size_t)rr * 16 * ND + k0);
      s0b2[rr] = *(const f32x4*)(b2p + (size_t)rr * 16 * ND + k0);
    }
  };
  auto loadB_s1 = [&](int k0) {
#pragma unroll
    for (int rr = 0; rr < 4; ++rr) {
      s1b1[rr] = *(const f32x4*)(b1p + (size_t)rr * 16 * ND + k0);
      s1b2[rr] = *(const f32x4*)(b2p + (size_t)rr * 16 * ND + k0);
    }
  };
  auto writeB_s0 = [&](int buf) {
#pragma unroll
    for (int rr = 0; rr < 4; ++rr) {
      *(u16x4*)&B1s[buf][rr * 16 + rsub][c4] = cvt4(s0b1[rr]);
      *(u16x4*)&B2s[buf][rr * 16 + rsub][c4] = cvt4(s0b2[rr]);
    }
  };
  auto writeB_s1 = [&](int buf) {
#pragma unroll
    for (int rr = 0; rr < 4; ++rr) {
      *(u16x4*)&B1s[buf][rr * 16 + rsub][c4] = cvt4(s1b1[rr]);
      *(u16x4*)&B2s[buf][rr * 16 + rsub][c4] = cvt4(s1b2[rr]);
    }
  };

  int wm = (wid >> 1) * 64;
  int wn = (wid & 1) * 32;
  int rl = lane & 15;
  int ksel8 = (lane >> 4) * 8;
  int xorf = rl & 7;

  f32x4 acc1[4][2] = {}, acc2[4][2] = {};

  auto mfma = [&](int buf) {
#pragma unroll
    for (int kk = 0; kk < 2; ++kk) {
      int klo = kk * 32 + ksel8;
      int g = (klo >> 3) ^ xorf;
      bf16x8 af[4], b1v[2], b2v[2];
#pragma unroll
      for (int i = 0; i < 4; ++i) {
        int row = wm + i * 16 + rl;
        af[i] = *(const bf16x8*)((const char*)&As[buf][0][0] + row * 128 + (g << 4));
      }
#pragma unroll
      for (int j = 0; j < 2; ++j) {
        b1v[j] = *(const bf16x8*)&B1s[buf][wn + j * 16 + rl][klo];
        b2v[j] = *(const bf16x8*)&B2s[buf][wn + j * 16 + rl][klo];
      }
#pragma unroll
      for (int i = 0; i < 4; ++i)
#pragma unroll
        for (int j = 0; j < 2; ++j) {
          acc1[i][j] = __builtin_amdgcn_mfma_f32_16x16x32_bf16(af[i], b1v[j], acc1[i][j], 0, 0, 0);
          acc2[i][j] = __builtin_amdgcn_mfma_f32_16x16x32_bf16(af[i], b2v[j], acc2[i][j], 0, 0, 0);
        }
    }
  };

  stageA(0, 0);
  loadB_s0(0);
  loadB_s1(64);
  writeB_s0(0);
  __syncthreads();

  const int NSTEP = ND / 64;   // 16, even
  for (int ks = 0; ks < NSTEP; ks += 2) {
    // even step (buf0 = step ks)
    stageA(1, ks + 1);
    if (ks + 2 < NSTEP) loadB_s0((ks + 2) * 64);
    mfma(0);
    writeB_s1(1);
    __syncthreads();
    // odd step (buf1 = step ks+1)
    if (ks + 2 < NSTEP) stageA(0, ks + 2);
    if (ks + 3 < NSTEP) loadB_s1((ks + 3) * 64);
    mfma(1);
    if (ks + 2 < NSTEP) writeB_s0(0);
    __syncthreads();
  }

  // SwiGLU epilogue
  int rq = lane >> 4;
#pragma unroll
  for (int i = 0; i < 4; ++i)
#pragma unroll
    for (int r = 0; r < 4; ++r) {
      int mrow = wm + i * 16 + rq * 4 + r;
      int m = m0 + mrow;
      if (m < cnt) {
#pragma unroll
        for (int j = 0; j < 2; ++j) {
          int col = n0 + wn + j * 16 + rl;
          float g1 = acc1[i][j][r], g2 = acc2[i][j][r];
          float hv = g1 / (1.f + expf(-g1)) * g2;
          h[(size_t)(base + m) * NH + col] = __builtin_bit_cast(unsigned short, (__bf16)hv);
        }
      }
    }
}

// ---------------- GEMM3: out += h @ W3^T (split-K=2, atomicAdd) ----------------
__global__ __launch_bounds__(256, 4) void moe_gemm3(
    const unsigned short* __restrict__ h, const float* __restrict__ W3f,
    const int* __restrict__ offsets, const int* __restrict__ token_list,
    float* __restrict__ out)
{
  int e = blockIdx.z;
  int base = offsets[e], cnt = offsets[e + 1] - base;
  int m0 = blockIdx.y * 128;
  if (m0 >= cnt) return;
  int n0 = (blockIdx.x >> 1) * 64;
  int kc = blockIdx.x & 1;
  const int KOFF = kc * (NH / 2);
  const float* B = W3f + (size_t)e * ((size_t)ND * NH) + (size_t)n0 * NH + KOFF;

  __shared__ __align__(16) unsigned short As[2][128][64];
  __shared__ __align__(16) unsigned short Bs[2][64][LDK];
  __shared__ int rowtok[128];

  int t = threadIdx.x;
  if (t < 128) {
    int mc = m0 + t; if (mc > cnt - 1) mc = cnt - 1;
    rowtok[t] = token_list[base + mc];
  }
  __syncthreads();

  int lane = t & 63, wid = t >> 6;

  const char* aSrc[4];
  {
    int l8 = lane >> 3, blk = lane & 7;
    int sblk = blk ^ l8;
#pragma unroll
    for (int i = 0; i < 4; ++i) {
      int R = wid * 32 + i * 8 + l8;
      int mc = m0 + R; if (mc > cnt - 1) mc = cnt - 1;
      aSrc[i] = (const char*)(h + (size_t)(base + mc) * NH + KOFF + sblk * 8);
    }
  }
  unsigned aldsOff = wid * 4096;

  auto stageA = [&](int buf, int ks) {
    char* dst = (char*)&As[buf][0][0] + aldsOff;
#pragma unroll
    for (int i = 0; i < 4; ++i)
      gl_lds16(aSrc[i] + ks * 128, dst + i * 1024);
  };

  int rsub = t >> 4;
  int c4 = (t & 15) * 4;
  const float* bp = B + (size_t)rsub * NH + c4;

  f32x4 s0b[4], s1b[4];
  auto loadB_s0 = [&](int k0) {
#pragma unroll
    for (int rr = 0; rr < 4; ++rr) s0b[rr] = *(const f32x4*)(bp + (size_t)rr * 16 * NH + k0);
  };
  auto loadB_s1 = [&](int k0) {
#pragma unroll
    for (int rr = 0; rr < 4; ++rr) s1b[rr] = *(const f32x4*)(bp + (size_t)rr * 16 * NH + k0);
  };
  auto writeB_s0 = [&](int buf) {
#pragma unroll
    for (int rr = 0; rr < 4; ++rr) *(u16x4*)&Bs[buf][rr * 16 + rsub][c4] = cvt4(s0b[rr]);
  };
  auto writeB_s1 = [&](int buf) {
#pragma unroll
    for (int rr = 0; rr < 4; ++rr) *(u16x4*)&Bs[buf][rr * 16 + rsub][c4] = cvt4(s1b[rr]);
  };

  int wm = (wid >> 1) * 64;
  int wn = (wid & 1) * 32;
  int rl = lane & 15;
  int ksel8 = (lane >> 4) * 8;
  int xorf = rl & 7;

  f32x4 acc[4][2] = {};

  auto mfma = [&](int buf) {
#pragma unroll
    for (int kk = 0; kk < 2; ++kk) {
      int klo = kk * 32 + ksel8;
      int g = (klo >> 3) ^ xorf;
      bf16x8 af[4], bv[2];
#pragma unroll
      for (int i = 0; i < 4; ++i) {
        int row = wm + i * 16 + rl;
        af[i] = *(const bf16x8*)((const char*)&As[buf][0][0] + row * 128 + (g << 4));
      }
#pragma unroll
      for (int j = 0; j < 2; ++j) bv[j] = *(const bf16x8*)&Bs[buf][wn + j * 16 + rl][klo];
#pragma unroll
      for (int i = 0; i < 4; ++i)
#pragma unroll
        for (int j = 0; j < 2; ++j)
          acc[i][j] = __builtin_amdgcn_mfma_f32_16x16x32_bf16(af[i], bv[j], acc[i][j], 0, 0, 0);
    }
  };

  stageA(0, 0);
  loadB_s0(0);
  loadB_s1(64);
  writeB_s0(0);
  __syncthreads();

  const int NSTEP = (NH / 2) / 64;   // 28, even
  for (int ks = 0; ks < NSTEP; ks += 2) {
    stageA(1, ks + 1);
    if (ks + 2 < NSTEP) loadB_s0((ks + 2) * 64);
    mfma(0);
    writeB_s1(1);
    __syncthreads();
    if (ks + 2 < NSTEP) stageA(0, ks + 2);
    if (ks + 3 < NSTEP) loadB_s1((ks + 3) * 64);
    mfma(1);
    if (ks + 2 < NSTEP) writeB_s0(0);
    __syncthreads();
  }

  int rq = lane >> 4;
#pragma unroll
  for (int i = 0; i < 4; ++i)
#pragma unroll
    for (int r = 0; r < 4; ++r) {
      int mrow = wm + i * 16 + rq * 4 + r;
      int m = m0 + mrow;
      if (m < cnt) {
        int tok = rowtok[mrow];
#pragma unroll
        for (int j = 0; j < 2; ++j) {
          int col = n0 + wn + j * 16 + rl;
          atomicAdd(&out[(size_t)tok * ND + col], acc[i][j][r]);
        }
      }
    }
}

extern "C" void kernel_launch(void* const* d_in, const int* in_sizes, int n_in,
                              void* d_out, int out_size, void* d_ws, size_t ws_size,
                              hipStream_t stream)
{
  (void)in_sizes; (void)n_in; (void)out_size; (void)ws_size;
  const float* x  = (const float*)d_in[0];
  const float* Wr = (const float*)d_in[1];
  const float* W1 = (const float*)d_in[2];
  const float* W2 = (const float*)d_in[3];
  const float* W3 = (const float*)d_in[4];
  float* out = (float*)d_out;

  char* w = (char*)d_ws;
  float* probs    = (float*)(w + 0);        // 65536 B
  float* lse      = (float*)(w + 65536);    // 8192 B
  int* counts     = (int*)(w + 73728);      // 32 B
  int* cursors    = (int*)(w + 73760);      // 32 B
  int* offsets    = (int*)(w + 73792);      // 64 B
  int* expert_of  = (int*)(w + 73856);      // 8192 B
  int* token_list = (int*)(w + 82048);      // 8192 B
  unsigned short* h  = (unsigned short*)(w + 131072);            // 14680064 B
  unsigned short* xb = (unsigned short*)(w + 131072 + 14680064); // 4194304 B

  hipMemsetAsync(counts, 0, 32, stream);
  hipMemsetAsync(out, 0, (size_t)NTOK * ND * sizeof(float), stream);
  convert_x<<<NTOK * ND / (256 * 4), 256, 0, stream>>>(x, xb);
  router_kernel<<<NTOK, 256, 0, stream>>>(x, Wr, probs, lse, counts, expert_of);
  aux_offsets_kernel<<<1, 256, 0, stream>>>(probs, lse, counts, offsets, cursors,
                                            out + (size_t)NTOK * ND);
  scatter_kernel<<<NTOK / 256, 256, 0, stream>>>(expert_of, cursors, token_list);
  moe_gemm12<<<dim3(NH / 64, NTOK / 128, NE), 256, 0, stream>>>(
      xb, W1, W2, offsets, token_list, h);
  moe_gemm3<<<dim3((ND / 64) * 2, NTOK / 128, NE), 256, 0, stream>>>(
      h, W3, offsets, token_list, out);
}

// Round 5
// 198.487 us; speedup vs baseline: 1.7695x; 1.0595x over previous
//
#include <hip/hip_runtime.h>
#include <hip/hip_bf16.h>
#include <math.h>

// MoE: B=2,S=1024,D=1024,E=8,H=3584, top-1 routing.
// router(+x->bf16) -> aux -> scatter
//   -> gemm12 (x@W1^T, x@W2^T fused + SwiGLU -> h bf16)
//   -> gemm3  (h@W3^T, split-K=2, atomicAdd f32 -> out)
// GEMMs: bf16 MFMA 16x16x32, dbuf LDS, A via global_load_lds DMA (swizzled src),
// B reg-staged f32->bf16 2 sets. T4 counted-vmcnt barriers: keep next B-loads
// in flight across s_barrier (retire only the A-DMA being published).

#define NS 1024
#define ND 1024
#define NE 8
#define NH 3584
#define NTOK 2048
#define LDK 72   // +8 bf16 pad for B tiles

typedef float f32x4 __attribute__((ext_vector_type(4)));
typedef __bf16 bf16x8 __attribute__((ext_vector_type(8)));
typedef unsigned short u16x4 __attribute__((ext_vector_type(4)));
typedef unsigned int u32x4 __attribute__((ext_vector_type(4)));

// counted barrier: retire all but the newest N VMEM ops, publish LDS writes.
#define CBAR(N) asm volatile("s_waitcnt vmcnt(" #N ") lgkmcnt(0)\n\ts_barrier" ::: "memory")

__device__ __forceinline__ u16x4 cvt4(f32x4 v) {
  u16x4 r;
  r[0] = __builtin_bit_cast(unsigned short, (__bf16)v[0]);
  r[1] = __builtin_bit_cast(unsigned short, (__bf16)v[1]);
  r[2] = __builtin_bit_cast(unsigned short, (__bf16)v[2]);
  r[3] = __builtin_bit_cast(unsigned short, (__bf16)v[3]);
  return r;
}

__device__ __forceinline__ void gl_lds16(const void* g, void* l) {
  __builtin_amdgcn_global_load_lds(
      (const __attribute__((address_space(1))) unsigned int*)g,
      (__attribute__((address_space(3))) unsigned int*)l, 16, 0, 0);
}

// ---------------- router (+ x f32 -> bf16) ----------------
__global__ __launch_bounds__(256) void router_kernel(
    const float* __restrict__ x, const float* __restrict__ Wr,
    float* __restrict__ probs, float* __restrict__ lse,
    int* __restrict__ counts, int* __restrict__ expert_of,
    unsigned short* __restrict__ xb)
{
  int n = blockIdx.x;
  int t = threadIdx.x;
  const float* xr = x + (size_t)n * ND;
  float xv[4];
#pragma unroll
  for (int j = 0; j < 4; ++j) xv[j] = xr[t + j * 256];
  // fused convert
#pragma unroll
  for (int j = 0; j < 4; ++j)
    xb[(size_t)n * ND + t + j * 256] = __builtin_bit_cast(unsigned short, (__bf16)xv[j]);
  float p[NE];
#pragma unroll
  for (int e = 0; e < NE; ++e) p[e] = 0.f;
#pragma unroll
  for (int j = 0; j < 4; ++j) {
    int d = t + j * 256;
#pragma unroll
    for (int e = 0; e < NE; ++e) p[e] += xv[j] * Wr[e * ND + d];
  }
#pragma unroll
  for (int e = 0; e < NE; ++e) {
#pragma unroll
    for (int o = 32; o > 0; o >>= 1) p[e] += __shfl_down(p[e], o, 64);
  }
  __shared__ float red[4][NE];
  int wid = t >> 6, lane = t & 63;
  if (lane == 0) {
#pragma unroll
    for (int e = 0; e < NE; ++e) red[wid][e] = p[e];
  }
  __syncthreads();
  if (t == 0) {
    float lg[NE];
#pragma unroll
    for (int e = 0; e < NE; ++e) lg[e] = red[0][e] + red[1][e] + red[2][e] + red[3][e];
    float m = lg[0]; int arg = 0;
#pragma unroll
    for (int e = 1; e < NE; ++e) if (lg[e] > m) { m = lg[e]; arg = e; }
    float s = 0.f, ex[NE];
#pragma unroll
    for (int e = 0; e < NE; ++e) { ex[e] = expf(lg[e] - m); s += ex[e]; }
    float inv = 1.f / s;
#pragma unroll
    for (int e = 0; e < NE; ++e) probs[n * NE + e] = ex[e] * inv;
    lse[n] = m + logf(s);
    expert_of[n] = arg;
    atomicAdd(&counts[arg], 1);
  }
}

// ---------------- aux losses + offsets ----------------
__global__ __launch_bounds__(256) void aux_offsets_kernel(
    const float* __restrict__ probs, const float* __restrict__ lse,
    const int* __restrict__ counts, int* __restrict__ offsets,
    int* __restrict__ cursors, float* __restrict__ out_aux)
{
  int t = threadIdx.x;
  float lsum = 0.f;
  for (int n = t; n < NTOK; n += 256) lsum += lse[n];
  float esum = 0.f, esq = 0.f;
  for (int i = t; i < NS * NE; i += 256) {
    float v = probs[i] + probs[NS * NE + i];
    esum += v; esq += v * v;
  }
  __shared__ float rb[3][4];
  int wid = t >> 6, lane = t & 63;
#pragma unroll
  for (int o = 32; o > 0; o >>= 1) {
    lsum += __shfl_down(lsum, o, 64);
    esum += __shfl_down(esum, o, 64);
    esq  += __shfl_down(esq, o, 64);
  }
  if (lane == 0) { rb[0][wid] = lsum; rb[1][wid] = esum; rb[2][wid] = esq; }
  __syncthreads();
  if (t == 0) {
    lsum = rb[0][0] + rb[0][1] + rb[0][2] + rb[0][3];
    esum = rb[1][0] + rb[1][1] + rb[1][2] + rb[1][3];
    esq  = rb[2][0] + rb[2][1] + rb[2][2] + rb[2][3];
    float zmean = lsum / (float)NTOK;
    float z_loss = zmean * zmean;
    const float nn = (float)(NS * NE);
    float mean = esum / nn;
    float var = (esq - esum * esum / nn) / (nn - 1.0f);
    float load_loss = var / (mean * mean);
    out_aux[0] = 1e-3f * z_loss + 1e-3f * load_loss;
    int off = 0;
#pragma unroll
    for (int e = 0; e < NE; ++e) { offsets[e] = off; cursors[e] = off; off += counts[e]; }
    offsets[NE] = off;
  }
}

// ---------------- token lists ----------------
__global__ __launch_bounds__(256) void scatter_kernel(
    const int* __restrict__ expert_of, int* __restrict__ cursors,
    int* __restrict__ token_list)
{
  int n = blockIdx.x * 256 + threadIdx.x;
  int e = expert_of[n];
  int p = atomicAdd(&cursors[e], 1);
  token_list[p] = n;
}

// ---------------- fused GEMM12 + SwiGLU ----------------
__global__ __launch_bounds__(256) void moe_gemm12(
    const unsigned short* __restrict__ xb, const float* __restrict__ W1f,
    const float* __restrict__ W2f, const int* __restrict__ offsets,
    const int* __restrict__ token_list, unsigned short* __restrict__ h)
{
  int e = blockIdx.z;
  int base = offsets[e], cnt = offsets[e + 1] - base;
  int m0 = blockIdx.y * 128;
  if (m0 >= cnt) return;
  int n0 = blockIdx.x * 64;
  const float* B1 = W1f + (size_t)e * ((size_t)NH * ND) + (size_t)n0 * ND;
  const float* B2 = W2f + (size_t)e * ((size_t)NH * ND) + (size_t)n0 * ND;

  __shared__ __align__(16) unsigned short As[2][128][64];   // linear, XOR-swizzled content
  __shared__ __align__(16) unsigned short B1s[2][64][LDK];
  __shared__ __align__(16) unsigned short B2s[2][64][LDK];
  __shared__ int rowtok[128];

  int t = threadIdx.x;
  if (t < 128) {
    int mc = m0 + t; if (mc > cnt - 1) mc = cnt - 1;
    rowtok[t] = token_list[base + mc];
  }
  __syncthreads();

  int lane = t & 63, wid = t >> 6;

  const char* aSrc[4];
  {
    int l8 = lane >> 3, blk = lane & 7;
    int sblk = blk ^ l8;
#pragma unroll
    for (int i = 0; i < 4; ++i) {
      int R = wid * 32 + i * 8 + l8;
      aSrc[i] = (const char*)(xb + (size_t)rowtok[R] * ND + sblk * 8);
    }
  }
  unsigned aldsOff = wid * 4096;

  auto stageA = [&](int buf, int ks) {
    char* dst = (char*)&As[buf][0][0] + aldsOff;
#pragma unroll
    for (int i = 0; i < 4; ++i)
      gl_lds16(aSrc[i] + ks * 128, dst + i * 1024);
    __builtin_amdgcn_sched_barrier(0);   // pin DMA before B-loads (FIFO vmcnt count)
  };

  int rsub = t >> 4;
  int c4 = (t & 15) * 4;
  const float* b1p = B1 + (size_t)rsub * ND + c4;
  const float* b2p = B2 + (size_t)rsub * ND + c4;

  f32x4 s0b1[4], s0b2[4], s1b1[4], s1b2[4];

  auto loadB_s0 = [&](int k0) {
#pragma unroll
    for (int rr = 0; rr < 4; ++rr) {
      s0b1[rr] = *(const f32x4*)(b1p + (size_t)rr * 16 * ND + k0);
      s0b2[rr] = *(const f32x4*)(b2p + (size_t)rr * 16 * ND + k0);
    }
  };
  auto loadB_s1 = [&](int k0) {
#pragma unroll
    for (int rr = 0; rr < 4; ++rr) {
      s1b1[rr] = *(const f32x4*)(b1p + (size_t)rr * 16 * ND + k0);
      s1b2[rr] = *(const f32x4*)(b2p + (size_t)rr * 16 * ND + k0);
    }
  };
  auto writeB_s0 = [&](int buf) {
#pragma unroll
    for (int rr = 0; rr < 4; ++rr) {
      *(u16x4*)&B1s[buf][rr * 16 + rsub][c4] = cvt4(s0b1[rr]);
      *(u16x4*)&B2s[buf][rr * 16 + rsub][c4] = cvt4(s0b2[rr]);
    }
  };
  auto writeB_s1 = [&](int buf) {
#pragma unroll
    for (int rr = 0; rr < 4; ++rr) {
      *(u16x4*)&B1s[buf][rr * 16 + rsub][c4] = cvt4(s1b1[rr]);
      *(u16x4*)&B2s[buf][rr * 16 + rsub][c4] = cvt4(s1b2[rr]);
    }
  };

  int wm = (wid >> 1) * 64;
  int wn = (wid & 1) * 32;
  int rl = lane & 15;
  int ksel8 = (lane >> 4) * 8;
  int xorf = rl & 7;

  f32x4 acc1[4][2] = {}, acc2[4][2] = {};

  auto mfma = [&](int buf) {
#pragma unroll
    for (int kk = 0; kk < 2; ++kk) {
      int klo = kk * 32 + ksel8;
      int g = (klo >> 3) ^ xorf;
      bf16x8 af[4], b1v[2], b2v[2];
#pragma unroll
      for (int i = 0; i < 4; ++i) {
        int row = wm + i * 16 + rl;
        af[i] = *(const bf16x8*)((const char*)&As[buf][0][0] + row * 128 + (g << 4));
      }
#pragma unroll
      for (int j = 0; j < 2; ++j) {
        b1v[j] = *(const bf16x8*)&B1s[buf][wn + j * 16 + rl][klo];
        b2v[j] = *(const bf16x8*)&B2s[buf][wn + j * 16 + rl][klo];
      }
#pragma unroll
      for (int i = 0; i < 4; ++i)
#pragma unroll
        for (int j = 0; j < 2; ++j) {
          acc1[i][j] = __builtin_amdgcn_mfma_f32_16x16x32_bf16(af[i], b1v[j], acc1[i][j], 0, 0, 0);
          acc2[i][j] = __builtin_amdgcn_mfma_f32_16x16x32_bf16(af[i], b2v[j], acc2[i][j], 0, 0, 0);
        }
    }
  };

  // prologue: buf0 <- step0 (A DMA + B regs->LDS); s1 <- B(step1)
  stageA(0, 0);
  loadB_s0(0);
  loadB_s1(64);
  writeB_s0(0);        // compiler waits vmcnt to retire ADMA0+s0
  CBAR(8);             // keep s1 in flight

  const int NSTEP = ND / 64;   // 16
  // main: full prefetch, counted barriers; computes steps 0..NSTEP-3
  for (int ks = 0; ks <= NSTEP - 4; ks += 2) {
    stageA(1, ks + 1);
    loadB_s0((ks + 2) * 64);
    mfma(0);
    writeB_s1(1);            // compiler: vmcnt retires s1, keeps ADMA+s0
    CBAR(8);                 // retire ADMA(ks+1); keep s0 (8) in flight
    stageA(0, ks + 2);
    loadB_s1((ks + 3) * 64);
    mfma(1);
    writeB_s0(0);
    CBAR(8);                 // retire ADMA(ks+2); keep s1 in flight
  }
  // epilogue: steps NSTEP-2, NSTEP-1 (s1 holds B(NSTEP-1); buf0 ready)
  stageA(1, NSTEP - 1);
  mfma(0);
  writeB_s1(1);
  __syncthreads();           // full drain (ADMA + LDS publish)
  mfma(1);

  // SwiGLU epilogue
  int rq = lane >> 4;
#pragma unroll
  for (int i = 0; i < 4; ++i)
#pragma unroll
    for (int r = 0; r < 4; ++r) {
      int mrow = wm + i * 16 + rq * 4 + r;
      int m = m0 + mrow;
      if (m < cnt) {
#pragma unroll
        for (int j = 0; j < 2; ++j) {
          int col = n0 + wn + j * 16 + rl;
          float g1 = acc1[i][j][r], g2 = acc2[i][j][r];
          float hv = g1 / (1.f + expf(-g1)) * g2;
          h[(size_t)(base + m) * NH + col] = __builtin_bit_cast(unsigned short, (__bf16)hv);
        }
      }
    }
}

// ---------------- GEMM3: out += h @ W3^T (split-K=2, atomicAdd) ----------------
__global__ __launch_bounds__(256, 4) void moe_gemm3(
    const unsigned short* __restrict__ h, const float* __restrict__ W3f,
    const int* __restrict__ offsets, const int* __restrict__ token_list,
    float* __restrict__ out)
{
  int e = blockIdx.z;
  int base = offsets[e], cnt = offsets[e + 1] - base;
  int m0 = blockIdx.y * 128;
  if (m0 >= cnt) return;
  int n0 = (blockIdx.x >> 1) * 64;
  int kc = blockIdx.x & 1;
  const int KOFF = kc * (NH / 2);
  const float* B = W3f + (size_t)e * ((size_t)ND * NH) + (size_t)n0 * NH + KOFF;

  __shared__ __align__(16) unsigned short As[2][128][64];
  __shared__ __align__(16) unsigned short Bs[2][64][LDK];
  __shared__ int rowtok[128];

  int t = threadIdx.x;
  if (t < 128) {
    int mc = m0 + t; if (mc > cnt - 1) mc = cnt - 1;
    rowtok[t] = token_list[base + mc];
  }
  __syncthreads();

  int lane = t & 63, wid = t >> 6;

  const char* aSrc[4];
  {
    int l8 = lane >> 3, blk = lane & 7;
    int sblk = blk ^ l8;
#pragma unroll
    for (int i = 0; i < 4; ++i) {
      int R = wid * 32 + i * 8 + l8;
      int mc = m0 + R; if (mc > cnt - 1) mc = cnt - 1;
      aSrc[i] = (const char*)(h + (size_t)(base + mc) * NH + KOFF + sblk * 8);
    }
  }
  unsigned aldsOff = wid * 4096;

  auto stageA = [&](int buf, int ks) {
    char* dst = (char*)&As[buf][0][0] + aldsOff;
#pragma unroll
    for (int i = 0; i < 4; ++i)
      gl_lds16(aSrc[i] + ks * 128, dst + i * 1024);
    __builtin_amdgcn_sched_barrier(0);
  };

  int rsub = t >> 4;
  int c4 = (t & 15) * 4;
  const float* bp = B + (size_t)rsub * NH + c4;

  f32x4 s0b[4], s1b[4];
  auto loadB_s0 = [&](int k0) {
#pragma unroll
    for (int rr = 0; rr < 4; ++rr) s0b[rr] = *(const f32x4*)(bp + (size_t)rr * 16 * NH + k0);
  };
  auto loadB_s1 = [&](int k0) {
#pragma unroll
    for (int rr = 0; rr < 4; ++rr) s1b[rr] = *(const f32x4*)(bp + (size_t)rr * 16 * NH + k0);
  };
  auto writeB_s0 = [&](int buf) {
#pragma unroll
    for (int rr = 0; rr < 4; ++rr) *(u16x4*)&Bs[buf][rr * 16 + rsub][c4] = cvt4(s0b[rr]);
  };
  auto writeB_s1 = [&](int buf) {
#pragma unroll
    for (int rr = 0; rr < 4; ++rr) *(u16x4*)&Bs[buf][rr * 16 + rsub][c4] = cvt4(s1b[rr]);
  };

  int wm = (wid >> 1) * 64;
  int wn = (wid & 1) * 32;
  int rl = lane & 15;
  int ksel8 = (lane >> 4) * 8;
  int xorf = rl & 7;

  f32x4 acc[4][2] = {};

  auto mfma = [&](int buf) {
#pragma unroll
    for (int kk = 0; kk < 2; ++kk) {
      int klo = kk * 32 + ksel8;
      int g = (klo >> 3) ^ xorf;
      bf16x8 af[4], bv[2];
#pragma unroll
      for (int i = 0; i < 4; ++i) {
        int row = wm + i * 16 + rl;
        af[i] = *(const bf16x8*)((const char*)&As[buf][0][0] + row * 128 + (g << 4));
      }
#pragma unroll
      for (int j = 0; j < 2; ++j) bv[j] = *(const bf16x8*)&Bs[buf][wn + j * 16 + rl][klo];
#pragma unroll
      for (int i = 0; i < 4; ++i)
#pragma unroll
        for (int j = 0; j < 2; ++j)
          acc[i][j] = __builtin_amdgcn_mfma_f32_16x16x32_bf16(af[i], bv[j], acc[i][j], 0, 0, 0);
    }
  };

  stageA(0, 0);
  loadB_s0(0);
  loadB_s1(64);
  writeB_s0(0);
  CBAR(4);

  const int NSTEP = (NH / 2) / 64;   // 28
  for (int ks = 0; ks <= NSTEP - 4; ks += 2) {
    stageA(1, ks + 1);
    loadB_s0((ks + 2) * 64);
    mfma(0);
    writeB_s1(1);
    CBAR(4);
    stageA(0, ks + 2);
    loadB_s1((ks + 3) * 64);
    mfma(1);
    writeB_s0(0);
    CBAR(4);
  }
  stageA(1, NSTEP - 1);
  mfma(0);
  writeB_s1(1);
  __syncthreads();
  mfma(1);

  int rq = lane >> 4;
#pragma unroll
  for (int i = 0; i < 4; ++i)
#pragma unroll
    for (int r = 0; r < 4; ++r) {
      int mrow = wm + i * 16 + rq * 4 + r;
      int m = m0 + mrow;
      if (m < cnt) {
        int tok = rowtok[mrow];
#pragma unroll
        for (int j = 0; j < 2; ++j) {
          int col = n0 + wn + j * 16 + rl;
          atomicAdd(&out[(size_t)tok * ND + col], acc[i][j][r]);
        }
      }
    }
}

extern "C" void kernel_launch(void* const* d_in, const int* in_sizes, int n_in,
                              void* d_out, int out_size, void* d_ws, size_t ws_size,
                              hipStream_t stream)
{
  (void)in_sizes; (void)n_in; (void)out_size; (void)ws_size;
  const float* x  = (const float*)d_in[0];
  const float* Wr = (const float*)d_in[1];
  const float* W1 = (const float*)d_in[2];
  const float* W2 = (const float*)d_in[3];
  const float* W3 = (const float*)d_in[4];
  float* out = (float*)d_out;

  char* w = (char*)d_ws;
  float* probs    = (float*)(w + 0);        // 65536 B
  float* lse      = (float*)(w + 65536);    // 8192 B
  int* counts     = (int*)(w + 73728);      // 32 B
  int* cursors    = (int*)(w + 73760);      // 32 B
  int* offsets    = (int*)(w + 73792);      // 64 B
  int* expert_of  = (int*)(w + 73856);      // 8192 B
  int* token_list = (int*)(w + 82048);      // 8192 B
  unsigned short* h  = (unsigned short*)(w + 131072);            // 14680064 B
  unsigned short* xb = (unsigned short*)(w + 131072 + 14680064); // 4194304 B

  hipMemsetAsync(counts, 0, 32, stream);
  hipMemsetAsync(out, 0, (size_t)NTOK * ND * sizeof(float), stream);
  router_kernel<<<NTOK, 256, 0, stream>>>(x, Wr, probs, lse, counts, expert_of, xb);
  aux_offsets_kernel<<<1, 256, 0, stream>>>(probs, lse, counts, offsets, cursors,
                                            out + (size_t)NTOK * ND);
  scatter_kernel<<<NTOK / 256, 256, 0, stream>>>(expert_of, cursors, token_list);
  moe_gemm12<<<dim3(NH / 64, NTOK / 128, NE), 256, 0, stream>>>(
      xb, W1, W2, offsets, token_list, h);
  moe_gemm3<<<dim3((ND / 64) * 2, NTOK / 128, NE), 256, 0, stream>>>(
      h, W3, offsets, token_list, out);
}